// Round 1
// 314.378 us; speedup vs baseline: 1.1196x; 1.1196x over previous
//
#include <hip/hip_runtime.h>

#define BATCH 8
#define CCH 256
#define NPOS 4096
#define LOG2E 1.4426950408889634f

typedef __bf16 bf16x8 __attribute__((ext_vector_type(8)));
typedef float f32x4 __attribute__((ext_vector_type(4)));
typedef int i32x4 __attribute__((ext_vector_type(4)));

typedef const __attribute__((address_space(1))) void GAS;
typedef __attribute__((address_space(3))) void LAS;

#define CFENCE() __asm__ volatile("" ::: "memory")
// vmcnt(8), lgkmcnt no-wait(15), expcnt no-wait(7): (15<<8)|(7<<4)|8
#define WAIT_VM8()  do { CFENCE(); __builtin_amdgcn_s_waitcnt(0x0F78); CFENCE(); } while (0)
// lgkmcnt(0), vmcnt no-wait(63: low4=15,hi2=3), expcnt no-wait
#define WAIT_LGKM0() do { CFENCE(); __builtin_amdgcn_s_waitcnt(0xC07F); CFENCE(); } while (0)
#define BAR_RAW() do { CFENCE(); __builtin_amdgcn_s_barrier(); CFENCE(); } while (0)

__device__ __forceinline__ unsigned short f2bf(float f) {
  unsigned u = __builtin_bit_cast(unsigned, f);
  u += 0x7fffu + ((u >> 16) & 1u);
  return (unsigned short)(u >> 16);
}

__device__ __forceinline__ bf16x8 ld_bf8(const unsigned short* p) {
  i32x4 t = *reinterpret_cast<const i32x4*>(p);
  return __builtin_bit_cast(bf16x8, t);
}

// DPP row_ror rotate (16-lane rows) — pure-VALU cross-lane for reductions.
// CTRL = 0x120 | n  (row_ror:n). bound_ctrl=false + full masks: all lanes valid.
template<int CTRL>
__device__ __forceinline__ float dpp_rorf(float x) {
  return __builtin_bit_cast(float,
      __builtin_amdgcn_update_dpp(0, __builtin_bit_cast(int, x), CTRL, 0xF, 0xF, false));
}

__device__ __forceinline__ float fexp2(float x) {
#if __has_builtin(__builtin_amdgcn_exp2f)
  return __builtin_amdgcn_exp2f(x);
#else
  return __expf(x * 0.6931471805599453f);
#endif
}

// ---------------------------------------------------------------- kernel 1
__global__ void cvt_kernel(const float* __restrict__ Wq,
                           const float* __restrict__ Wk,
                           const float* __restrict__ Wv,
                           unsigned short* __restrict__ dst)
{
  const int idx = blockIdx.x * 256 + threadIdx.x;   // 0..196607
  const float* src = (idx < 65536) ? Wq : ((idx < 131072) ? Wk : Wv);
  dst[idx] = f2bf(src[idx & 65535]);
}

// ---------------------------------------------------------------- kernel 2
// Single pass per (b, pos-tile): x tile staged ONCE (coalesced, position-major
// reads), then 3 selectors x 4 o-strips computed from register-resident W.
// q is pre-scaled by log2(e) so attn softmax runs in the exp2 domain.
__global__ __launch_bounds__(256, 3)
void qkv_kernel(const float* __restrict__ x,
                const unsigned short* __restrict__ Wall,   // Wq|Wk|Wv bf16
                const float* __restrict__ bq,
                const float* __restrict__ bk,
                const float* __restrict__ bv,
                unsigned short* __restrict__ qT,
                unsigned short* __restrict__ kT,
                unsigned short* __restrict__ vG)
{
  __shared__ __align__(16) unsigned short xT[64 * 264];   // 33792 B
  __shared__ __align__(16) unsigned short tbuf[64 * 72];  //  9216 B transpose buf

  const int b   = blockIdx.x;
  const int i0  = blockIdx.y * 64;
  const int tid = threadIdx.x;
  const int w   = tid >> 6;
  const int l   = tid & 63;
  const int n   = l & 15;
  const int q4  = l >> 4;

  // stage x tile, coalesced: 16 lanes read one contiguous 256B channel row
  {
    const int li = tid & 15;     // position quad within tile
    const int cg = tid >> 4;     // channel within 16-channel group
#pragma unroll
    for (int it = 0; it < 16; ++it) {
      const int c = it * 16 + cg;
      f32x4 f = *reinterpret_cast<const f32x4*>(x + ((size_t)b * CCH + c) * NPOS + i0 + li * 4);
#pragma unroll
      for (int e = 0; e < 4; ++e) xT[(li * 4 + e) * 264 + c] = f2bf(f[e]);
    }
  }
  __syncthreads();

  const size_t qbase = (size_t)b * NPOS * CCH;
  bool first = true;

  for (int s = 0; s < 3; ++s) {
    const float* bias = (s == 0) ? bq : (s == 1) ? bk : bv;
    for (int op = 0; op < 4; ++op) {
      const int obase = op * 64;

      // A = W rows [obase + w*16 .. +16), register resident (8 frags)
      const unsigned short* Wp = Wall + s * 65536 + (size_t)(obase + w * 16 + n) * CCH + q4 * 8;
      bf16x8 wfr[8];
#pragma unroll
      for (int kk = 0; kk < 8; ++kk) wfr[kk] = ld_bf8(Wp + kk * 32);

      float bo[4];
#pragma unroll
      for (int r = 0; r < 4; ++r) bo[r] = bias[obase + w * 16 + q4 * 4 + r];

      f32x4 acc[4];
#pragma unroll
      for (int pt = 0; pt < 4; ++pt) {
        acc[pt] = {0.f, 0.f, 0.f, 0.f};
#pragma unroll
        for (int kk = 0; kk < 8; ++kk) {
          bf16x8 bfr = ld_bf8(&xT[(pt * 16 + n) * 264 + kk * 32 + q4 * 8]);
          acc[pt] = __builtin_amdgcn_mfma_f32_16x16x32_bf16(wfr[kk], bfr, acc[pt], 0, 0, 0);
        }
      }

      if (!first) __syncthreads();     // tbuf consumed by previous phase's store
      first = false;
      // D layout: col = lane&15 = pos, row = o-local = w*16 + q4*4 + r
      if (s < 2) {
        const float sc = (s == 0) ? LOG2E : 1.0f;
#pragma unroll
        for (int pt = 0; pt < 4; ++pt)
#pragma unroll
          for (int r = 0; r < 4; ++r)
            tbuf[(pt * 16 + n) * 72 + w * 16 + q4 * 4 + r] = f2bf((acc[pt][r] + bo[r]) * sc);
      } else {
#pragma unroll
        for (int pt = 0; pt < 4; ++pt)
#pragma unroll
          for (int r = 0; r < 4; ++r)
            tbuf[(w * 16 + q4 * 4 + r) * 72 + pt * 16 + n] = f2bf(acc[pt][r] + bo[r]);
      }
      __syncthreads();

      if (s < 2) {
        unsigned short* dst = (s == 0 ? qT : kT) + qbase;
#pragma unroll
        for (int it2 = 0; it2 < 2; ++it2) {
          const int idx = it2 * 256 + tid;
          const int pos = idx >> 3, ow = (idx & 7) * 8;
          i32x4 d = *reinterpret_cast<const i32x4*>(&tbuf[pos * 72 + ow]);
          *reinterpret_cast<i32x4*>(&dst[(size_t)(i0 + pos) * CCH + obase + ow]) = d;
        }
      } else {
#pragma unroll
        for (int it2 = 0; it2 < 2; ++it2) {
          const int idx = it2 * 256 + tid;
          const int o = idx >> 3, pw = (idx & 7) * 8;
          i32x4 d = *reinterpret_cast<const i32x4*>(&tbuf[o * 72 + pw]);
          *reinterpret_cast<i32x4*>(&vG[qbase + (size_t)(obase + o) * NPOS + i0 + pw]) = d;
        }
      }
    }
  }
}

// ---------------------------------------------------------------- kernel 3
// Flash attention:
//  - K: async global_load_lds into XOR-swizzled unpadded double buffer
//  - V: per-lane b128 loads straight from global (L2), prefetched at iter top
//  - P: XOR-swizzled [64][64] buffer (was 8-way bank conflicted at stride 72)
//  - softmax reduce: DPP row_ror rotate-reduce (no ds_swizzle), exp2 domain
//  - 2 raw barriers/iter, explicit vmcnt(8): K[jt+1] DMA stays in flight
__global__ __launch_bounds__(256, 2)
void attn_kernel(const unsigned short* __restrict__ qT,
                 const unsigned short* __restrict__ kT,
                 const unsigned short* __restrict__ vG,
                 const float* __restrict__ x,
                 const float* __restrict__ gamma,
                 float* __restrict__ out)
{
  __shared__ __align__(16) unsigned short kbuf[2][64 * 256];  // 2 x 32768 B, swizzled
  __shared__ __align__(16) unsigned short pbuf[64 * 64];      //  8192 B, swizzled
  __shared__ float stat_lds[64];

  const int b   = blockIdx.x;
  const int i0  = blockIdx.y * 64;
  const int tid = threadIdx.x;
  const int w   = tid >> 6;
  const int l   = tid & 63;
  const int n   = l & 15;
  const int q4  = l >> 4;
  const int nsw = n & 7;

  const unsigned short* qTb = qT + (size_t)b * NPOS * CCH;
  const unsigned short* kTb = kT + (size_t)b * NPOS * CCH;
  const unsigned short* vb  = vG + (size_t)b * NPOS * CCH;

  // Q fragments register-resident (A[m=lane&15][k=quad*8+j]) — pre-scaled by log2e
  bf16x8 afr[8];
  {
    const unsigned short* qrow = qTb + (size_t)(i0 + w * 16 + n) * CCH + q4 * 8;
#pragma unroll
    for (int kk = 0; kk < 8; ++kk)
      afr[kk] = ld_bf8(qrow + kk * 32);
  }

  // stage K[0]: wave issues 8 DMA loads, instruction t covers local rows 2t,2t+1.
  // LDS granule (j,gp) holds logical granule g = gp ^ (j&7)  (bank-spread swizzle).
  {
#pragma unroll
    for (int it = 0; it < 8; ++it) {
      const int t = w * 8 + it;
      const int j = 2 * t + (l >> 5);
      const int gp = l & 31;
      const int g  = gp ^ (j & 7);
      const unsigned short* src = kTb + (size_t)j * CCH + g * 8;
      unsigned short* dst = &kbuf[0][t * 512];    // wave-uniform base
      __builtin_amdgcn_global_load_lds((GAS*)src, (LAS*)dst, 16, 0, 0);
    }
  }

  f32x4 O[16];   // [ct*4+it]: c in [w*64+ct*16,+16), i in [it*16,+16)
#pragma unroll
  for (int t = 0; t < 16; ++t) O[t] = {0.f, 0.f, 0.f, 0.f};
  float mrow[4] = {-1e30f, -1e30f, -1e30f, -1e30f};
  float lrow[4] = {0.f, 0.f, 0.f, 0.f};

  for (int jt = 0; jt < 64; ++jt) {
    const int j0 = jt * 64;
    const unsigned short* kb = kbuf[jt & 1];

    // prefetch V[jt] into registers (always the 8 NEWEST vmem ops)
    i32x4 vreg[8];
#pragma unroll
    for (int ct = 0; ct < 4; ++ct) {
      const unsigned short* vp = vb + (size_t)(w * 64 + ct * 16 + n) * NPOS + j0 + q4 * 8;
      vreg[ct * 2]     = *reinterpret_cast<const i32x4*>(vp);
      vreg[ct * 2 + 1] = *reinterpret_cast<const i32x4*>(vp + 32);
    }

    WAIT_VM8();     // drain everything older than V[jt] => K[jt] DMA complete
    BAR_RAW();      // all waves' K[jt] in LDS; pbuf/stat free (readers done pre-barrier)

    // S = Q K^T  (swizzled K reads: physical granule = (kk*4+q4) ^ (n&7))
    f32x4 sacc[4];
#pragma unroll
    for (int nt = 0; nt < 4; ++nt) {
      const unsigned short* krow = kb + (nt * 16 + n) * 256;
      sacc[nt] = {0.f, 0.f, 0.f, 0.f};
#pragma unroll
      for (int kk = 0; kk < 8; ++kk) {
        const int gp = (kk * 4 + q4) ^ nsw;
        bf16x8 bfr = ld_bf8(krow + gp * 8);
        sacc[nt] = __builtin_amdgcn_mfma_f32_16x16x32_bf16(afr[kk], bfr, sacc[nt], 0, 0, 0);
      }
    }

    // online softmax in exp2 domain (row = q4*4 + r, DPP rotate reduce over 16 lanes)
    float a_r[4];
#pragma unroll
    for (int r = 0; r < 4; ++r) {
      float tm = fmaxf(fmaxf(sacc[0][r], sacc[1][r]), fmaxf(sacc[2][r], sacc[3][r]));
      tm = fmaxf(tm, dpp_rorf<0x121>(tm));
      tm = fmaxf(tm, dpp_rorf<0x122>(tm));
      tm = fmaxf(tm, dpp_rorf<0x124>(tm));
      tm = fmaxf(tm, dpp_rorf<0x128>(tm));
      const float mnew = fmaxf(mrow[r], tm);
      a_r[r] = fexp2(mrow[r] - mnew);
      float s = 0.f;
#pragma unroll
      for (int nt = 0; nt < 4; ++nt) {
        const float p = fexp2(sacc[nt][r] - mnew);
        sacc[nt][r] = p;
        s += p;
      }
      s += dpp_rorf<0x121>(s);
      s += dpp_rorf<0x122>(s);
      s += dpp_rorf<0x124>(s);
      s += dpp_rorf<0x128>(s);
      lrow[r] = lrow[r] * a_r[r] + s;
      mrow[r] = mnew;
    }

    if (n == 0) {
#pragma unroll
      for (int r = 0; r < 4; ++r) stat_lds[w * 16 + q4 * 4 + r] = a_r[r];
    }
    // P -> LDS, XOR-swizzled granules: phys granule = (col>>3) ^ (row&7)
#pragma unroll
    for (int r = 0; r < 4; ++r) {
      const int row = w * 16 + q4 * 4 + r;
      const int rs  = row & 7;
#pragma unroll
      for (int nt = 0; nt < 4; ++nt) {
        const int g = nt * 2 + (n >> 3);
        pbuf[row * 64 + ((g ^ rs) << 3) + (n & 7)] = f2bf(sacc[nt][r]);
      }
    }

    // prefetch K[jt+1] DMA into other buffer (UNCONDITIONAL, wrapped: keeps
    // compiler's V-use wait at vmcnt(8) instead of vmcnt(0))
    {
      const int j0n = ((jt + 1) & 63) * 64;
      unsigned short* bufn = kbuf[(jt + 1) & 1];
#pragma unroll
      for (int it = 0; it < 8; ++it) {
        const int t = w * 8 + it;
        const int j = 2 * t + (l >> 5);
        const int gp = l & 31;
        const int g  = gp ^ (j & 7);
        const unsigned short* src = kTb + (size_t)(j0n + j) * CCH + g * 8;
        unsigned short* dst = &bufn[t * 512];
        __builtin_amdgcn_global_load_lds((GAS*)src, (LAS*)dst, 16, 0, 0);
      }
    }

    WAIT_LGKM0();   // my P/stat writes landed
    BAR_RAW();      // P + alpha visible to all; K' DMA still in flight

    // rescale O by alpha
#pragma unroll
    for (int it = 0; it < 4; ++it) {
      const float al = stat_lds[it * 16 + n];
#pragma unroll
      for (int ct = 0; ct < 4; ++ct) {
        f32x4& o = O[ct * 4 + it];
        o[0] *= al; o[1] *= al; o[2] *= al; o[3] *= al;
      }
    }

    // PV: V from registers, P from swizzled LDS
    bf16x8 pf[8];
#pragma unroll
    for (int it = 0; it < 4; ++it) {
      const int rowb = (it * 16 + n) * 64;
      pf[it * 2 + 0] = ld_bf8(&pbuf[rowb + ((q4 ^ nsw) << 3)]);
      pf[it * 2 + 1] = ld_bf8(&pbuf[rowb + (((4 + q4) ^ nsw) << 3)]);
    }
#pragma unroll
    for (int ct = 0; ct < 4; ++ct) {
      bf16x8 vf0 = __builtin_bit_cast(bf16x8, vreg[ct * 2]);
      bf16x8 vf1 = __builtin_bit_cast(bf16x8, vreg[ct * 2 + 1]);
#pragma unroll
      for (int it = 0; it < 4; ++it) {
        O[ct * 4 + it] = __builtin_amdgcn_mfma_f32_16x16x32_bf16(vf0, pf[it * 2 + 0], O[ct * 4 + it], 0, 0, 0);
        O[ct * 4 + it] = __builtin_amdgcn_mfma_f32_16x16x32_bf16(vf1, pf[it * 2 + 1], O[ct * 4 + it], 0, 0, 0);
      }
    }
  }

  // epilogue: y = x + gamma * O / l   (full-drain syncthreads fine here)
  __syncthreads();
  if (n == 0) {
#pragma unroll
    for (int r = 0; r < 4; ++r) stat_lds[w * 16 + q4 * 4 + r] = lrow[r];
  }
  __syncthreads();

  const float g = gamma[0];
#pragma unroll
  for (int it = 0; it < 4; ++it) {
    const float sc = g / stat_lds[it * 16 + n];
    const int ipos = i0 + it * 16 + n;
#pragma unroll
    for (int ct = 0; ct < 4; ++ct) {
#pragma unroll
      for (int r = 0; r < 4; ++r) {
        const int c = w * 64 + ct * 16 + q4 * 4 + r;
        const size_t idx = ((size_t)(b * CCH + c)) * NPOS + ipos;
        out[idx] = x[idx] + sc * O[ct * 4 + it][r];
      }
    }
  }
}

// ---------------------------------------------------------------- launch
extern "C" void kernel_launch(void* const* d_in, const int* in_sizes, int n_in,
                              void* d_out, int out_size, void* d_ws, size_t ws_size,
                              hipStream_t stream)
{
  const float* x     = (const float*)d_in[0];
  const float* Wq    = (const float*)d_in[1];
  const float* bq    = (const float*)d_in[2];
  const float* Wk    = (const float*)d_in[3];
  const float* bk    = (const float*)d_in[4];
  const float* Wv    = (const float*)d_in[5];
  const float* bv    = (const float*)d_in[6];
  const float* gamma = (const float*)d_in[7];
  float* out = (float*)d_out;

  unsigned short* ws   = (unsigned short*)d_ws;
  unsigned short* Wall = ws;                                  // 3 x 65536 bf16
  unsigned short* qT   = ws + 196608;                         // (B,N,C) bf16, pre-scaled log2e
  unsigned short* kT   = qT + (size_t)BATCH * NPOS * CCH;     // (B,N,C) bf16
  unsigned short* vG   = kT + (size_t)BATCH * NPOS * CCH;     // (B,C,N) bf16

  cvt_kernel<<<768, 256, 0, stream>>>(Wq, Wk, Wv, Wall);
  qkv_kernel<<<dim3(8, 64), 256, 0, stream>>>(x, Wall, bq, bk, bv, qT, kT, vG);
  attn_kernel<<<dim3(8, 64), 256, 0, stream>>>(qT, kT, vG, x, gamma, out);
}